// Round 5
// 7248.549 us; speedup vs baseline: 2.4211x; 2.4211x over previous
//
#include <hip/hip_runtime.h>
#include <hip/hip_bf16.h>
#include <stdint.h>

#define B_   32
#define T_   512
#define V_   8000
#define E_   256
#define U_   512
#define BT_  (B_*T_)       // 16384
#define G4_  (4*U_)        // 2048
#define GWG  32            // workgroups per direction in recurrence
#define UPW  (U_/GWG)      // 16 hidden units per WG

typedef unsigned short ushort_t;
typedef __attribute__((ext_vector_type(8))) short   short8;
typedef __attribute__((ext_vector_type(4))) float   floatx4;

__device__ __forceinline__ float bf2f(ushort_t u) {
    union { unsigned int i; float f; } v; v.i = ((unsigned int)u) << 16; return v.f;
}
__device__ __forceinline__ ushort_t f2bf(float f) {
    union { float f; unsigned int i; } v; v.f = f;
    unsigned int r = v.i + 0x7fffu + ((v.i >> 16) & 1u);   // RNE
    return (ushort_t)(r >> 16);
}
__device__ __forceinline__ float sigmoidf_(float x) { return 1.0f / (1.0f + __expf(-x)); }
__device__ __forceinline__ float tanhf_(float x) {
    float ax = fabsf(x);
    float e  = __expf(-2.0f * ax);
    float r  = (1.0f - e) / (1.0f + e);
    return copysignf(r, x);
}

// ---- agent-coherent (cross-XCD) mailbox accessors: bypass L1/L2, hit L3 ----
__device__ __forceinline__ void stg_h_sc1(ushort_t* p, unsigned int v) {
    asm volatile("global_store_short %0, %1, off sc0 sc1"
                 :: "v"(p), "v"(v) : "memory");
}
template<int OFFB>
__device__ __forceinline__ short8 ldg_h_sc1(const ushort_t* p) {
    short8 r;
    asm volatile("global_load_dwordx4 %0, %1, off offset:%2 sc0 sc1"
                 : "=&v"(r) : "v"(p), "i"(OFFB));
    return r;
}

// ---------------- embedding gather+cast: x[BT][E](bf16) = emb[tokens](f32) ----------------
__global__ void embed_kernel(const int* __restrict__ tokens,
                             const float* __restrict__ emb,
                             ushort_t* __restrict__ x)
{
    int row = blockIdx.x * 4 + (threadIdx.x >> 6);       // 4 rows / block
    int col = (threadIdx.x & 63) * 4;                    // 4 floats per thread
    int tok = tokens[row];
    const float4 v = *(const float4*)(emb + (size_t)tok * E_ + col);
    ushort_t* dst = x + (size_t)row * E_ + col;
    dst[0] = f2bf(v.x); dst[1] = f2bf(v.y); dst[2] = f2bf(v.z); dst[3] = f2bf(v.w);
}

// ---------------- f32 -> bf16 transpose: in[R][C](f32) -> out[C][R](bf16) ----------------
__global__ void transpose_f32_bf16(const float* __restrict__ in,
                                   ushort_t* __restrict__ out, int R, int C)
{
    __shared__ ushort_t tile[32][33];
    int c0 = blockIdx.x * 32, r0 = blockIdx.y * 32;
    int r = threadIdx.x >> 3;            // 0..31
    int c4 = (threadIdx.x & 7) * 4;      // 0..28
    const float* src = in + (size_t)(r0 + r) * C + c0 + c4;
    #pragma unroll
    for (int i = 0; i < 4; ++i) tile[r][c4 + i] = f2bf(src[i]);
    __syncthreads();
    ushort_t* dst = out + (size_t)(c0 + r) * R + r0 + c4;
    #pragma unroll
    for (int i = 0; i < 4; ++i) dst[i] = tile[c4 + i][r];
}

// ---------------- bf16 GEMM: C[M][Nd] = A[M][K] @ BT[N][K]^T + bias ----------------
// 128x128 tile, BK=32, 256 threads (2x2 waves of 64x64). Register staging.
// OUT_F32: store f32 (final logits) vs bf16 (intermediates).
template <bool OUT_F32>
__global__ __launch_bounds__(256)
void gemm_bt(const ushort_t* __restrict__ A,
             const ushort_t* __restrict__ BT,
             const float* __restrict__ bias,
             void* __restrict__ Cv,
             int M, int Nd, int K)
{
    const int tid = threadIdx.x, lane = tid & 63, wave = tid >> 6;
    const int wm = wave >> 1, wn = wave & 1;          // 2x2 waves, 64x64 each
    const int m0 = blockIdx.x * 128;
    const int n0 = blockIdx.y * 128;
    __shared__ __align__(16) ushort_t As[128 * 32];
    __shared__ __align__(16) ushort_t Bs[128 * 32];
    floatx4 acc[4][4];
    #pragma unroll
    for (int i = 0; i < 4; ++i)
        #pragma unroll
        for (int j = 0; j < 4; ++j) acc[i][j] = (floatx4){0.f, 0.f, 0.f, 0.f};

    const int lr = lane >> 2;          // 0..15: row within 16-row load group
    const int lk = (lane & 3) * 8;     // k elems within row
    const int rowL = wave * 32 + lr;   // LDS row of this lane's first vector (wave in 0..3)
    const int ra0 = m0 + rowL;
    int rb0 = n0 + rowL;      if (rb0 > Nd - 1) rb0 = Nd - 1;   // clamp (N edge)
    int rb1 = n0 + rowL + 16; if (rb1 > Nd - 1) rb1 = Nd - 1;

    for (int k0 = 0; k0 < K; k0 += 32) {
        uint4 a0 = *(const uint4*)(A  + (size_t)ra0        * K + k0 + lk);
        uint4 a1 = *(const uint4*)(A  + (size_t)(ra0 + 16) * K + k0 + lk);
        uint4 b0 = *(const uint4*)(BT + (size_t)rb0        * K + k0 + lk);
        uint4 b1 = *(const uint4*)(BT + (size_t)rb1        * K + k0 + lk);
        __syncthreads();               // previous iter's LDS reads complete
        *(uint4*)(As + (rowL     ) * 32 + lk) = a0;
        *(uint4*)(As + (rowL + 16) * 32 + lk) = a1;
        *(uint4*)(Bs + (rowL     ) * 32 + lk) = b0;
        *(uint4*)(Bs + (rowL + 16) * 32 + lk) = b1;
        __syncthreads();
        short8 af[4], bw[4];
        #pragma unroll
        for (int i = 0; i < 4; ++i)
            af[i] = *(const short8*)(As + (wm * 64 + i * 16 + (lane & 15)) * 32 + (lane >> 4) * 8);
        #pragma unroll
        for (int j = 0; j < 4; ++j)
            bw[j] = *(const short8*)(Bs + (wn * 64 + j * 16 + (lane & 15)) * 32 + (lane >> 4) * 8);
        #pragma unroll
        for (int i = 0; i < 4; ++i)
            #pragma unroll
            for (int j = 0; j < 4; ++j)
                acc[i][j] = __builtin_amdgcn_mfma_f32_16x16x32_bf16(af[i], bw[j], acc[i][j], 0, 0, 0);
    }
    // epilogue: C/D layout col(n)=lane&15, row(m)=(lane>>4)*4+r
    #pragma unroll
    for (int j = 0; j < 4; ++j) {
        int n = n0 + wn * 64 + j * 16 + (lane & 15);
        bool nok = (n < Nd);
        float bv = nok ? bias[nok ? n : 0] : 0.f;
        #pragma unroll
        for (int i = 0; i < 4; ++i) {
            #pragma unroll
            for (int r = 0; r < 4; ++r) {
                int m = m0 + wm * 64 + i * 16 + (lane >> 4) * 4 + r;
                if (nok) {
                    float v = acc[i][j][r] + bv;
                    if (OUT_F32) ((float*)Cv)[(size_t)m * Nd + n] = v;
                    else         ((ushort_t*)Cv)[(size_t)m * Nd + n] = f2bf(v);
                }
            }
        }
    }
}

// ---------------- masked bidirectional LSTM recurrence (one layer) ----------------
// grid = (GWG, 2 dirs), 512 threads (8 waves). Wave (mt,q) computes the 16x16
// z-tile for batch-tile mt (16 batches) and gate q over this WG's 16 units.
// Recurrent weight fragments live in registers (loaded once).
//
// Cross-WG h exchange is a pure sc1 (agent-coherent) mailbox:
//   writers: sc0/sc1 stores -> s_waitcnt vmcnt(0) -> barrier -> RELAXED agent add
//   readers: RELAXED agent spin (no buffer_inv per poll!) -> sc0/sc1 loads
// No __threadfence (no buffer_wbl2), no ACQUIRE spin (no per-poll L2 invalidate):
// the per-XCD L2 stays warm for the xw/token/weight streams.
__global__ __launch_bounds__(512)
void lstm_rec(const ushort_t* __restrict__ xw,     // [2][BT][2048] gate pre-activations (bf16)
              const ushort_t* __restrict__ WrTf,   // [2048][512]  transposed recurrent W (bf16)
              const ushort_t* __restrict__ WrTb,
              const int* __restrict__ tokens,      // [B][T]
              ushort_t* __restrict__ h,            // [BT][1024] output (fwd|bwd halves, bf16)
              int* __restrict__ cnt)               // [2][T] arrival counters (zeroed)
{
    const int tid  = threadIdx.x;
    const int lane = tid & 63;
    const int wave = tid >> 6;
    const int dir  = blockIdx.y;
    const int g    = blockIdx.x;
    const int mt   = wave >> 2;          // batch tile 0/1
    const int q    = wave & 3;           // gate i,f,g,o
    const int l16  = lane & 15;
    const int l4   = lane >> 4;
    const ushort_t* WrT = dir ? WrTb : WrTf;

    // B fragments: B[k][n] with n = q*512 + g*16 + l16, k = kb*32 + l4*8 + j
    short8 bfrag[16];
    {
        const ushort_t* src = WrT + (size_t)(q * U_ + g * UPW + l16) * U_ + l4 * 8;
        #pragma unroll
        for (int kb = 0; kb < 16; ++kb) bfrag[kb] = *(const short8*)(src + kb * 32);
    }

    __shared__ float zs[4][32][17];      // [gate][batch][unit] (+1 pad)

    const int b_me = tid >> 4;           // 0..31: this thread's batch
    const int u_me = tid & 15;           // 0..15: this thread's unit (local)
    const int u_g  = g * UPW + u_me;     // global unit within direction
    float c_st = 0.0f, h_st = 0.0f;
    const int cbase = dir * T_;

    for (int s = 0; s < T_; ++s) {
        const int t = dir ? (T_ - 1 - s) : s;
        // prefetch step-s inputs (independent of other WGs; overlaps the spin)
        const ushort_t* xwp = xw + ((size_t)dir * BT_ + (size_t)b_me * T_ + t) * G4_ + u_g;
        ushort_t xwi = xwp[0 * U_], xwf = xwp[1 * U_], xwg = xwp[2 * U_], xwo = xwp[3 * U_];
        int tok = tokens[b_me * T_ + t];

        floatx4 acc = (floatx4){0.f, 0.f, 0.f, 0.f};
        if (s > 0) {
            if (tid == 0) {
                // relaxed poll: no cache-maintenance ops emitted
                while (__hip_atomic_load(&cnt[cbase + s - 1], __ATOMIC_RELAXED,
                                         __HIP_MEMORY_SCOPE_AGENT) < GWG) { }
            }
            __syncthreads();                               // (A) spin broadcast
            const int tp = dir ? (t + 1) : (t - 1);
            const ushort_t* hp = h + ((size_t)(mt * 16 + l16) * T_ + tp) * (2 * U_)
                                   + dir * U_ + l4 * 8;
            short8 af[16];
            // 16 agent-coherent 16B loads, all in flight together
            af[0]  = ldg_h_sc1< 0 * 64>(hp);
            af[1]  = ldg_h_sc1< 1 * 64>(hp);
            af[2]  = ldg_h_sc1< 2 * 64>(hp);
            af[3]  = ldg_h_sc1< 3 * 64>(hp);
            af[4]  = ldg_h_sc1< 4 * 64>(hp);
            af[5]  = ldg_h_sc1< 5 * 64>(hp);
            af[6]  = ldg_h_sc1< 6 * 64>(hp);
            af[7]  = ldg_h_sc1< 7 * 64>(hp);
            af[8]  = ldg_h_sc1< 8 * 64>(hp);
            af[9]  = ldg_h_sc1< 9 * 64>(hp);
            af[10] = ldg_h_sc1<10 * 64>(hp);
            af[11] = ldg_h_sc1<11 * 64>(hp);
            af[12] = ldg_h_sc1<12 * 64>(hp);
            af[13] = ldg_h_sc1<13 * 64>(hp);
            af[14] = ldg_h_sc1<14 * 64>(hp);
            af[15] = ldg_h_sc1<15 * 64>(hp);
            // inline-asm loads are invisible to the compiler's waitcnt tracking:
            // explicit drain + scheduler fence before the MFMAs consume af[].
            asm volatile("s_waitcnt vmcnt(0)" ::: "memory");
            __builtin_amdgcn_sched_barrier(0);
            #pragma unroll
            for (int kb = 0; kb < 16; ++kb)
                acc = __builtin_amdgcn_mfma_f32_16x16x32_bf16(af[kb], bfrag[kb], acc, 0, 0, 0);
        }
        // scatter z tile to LDS (C layout: col=l16 -> unit, row=l4*4+r -> batch)
        #pragma unroll
        for (int r = 0; r < 4; ++r)
            zs[q][mt * 16 + l4 * 4 + r][l16] = acc[r];
        __syncthreads();                                   // (B)

        float zi = bf2f(xwi) + zs[0][b_me][u_me];
        float zf = bf2f(xwf) + zs[1][b_me][u_me];
        float zg = bf2f(xwg) + zs[2][b_me][u_me];
        float zo = bf2f(xwo) + zs[3][b_me][u_me];
        float c_new = sigmoidf_(zf) * c_st + sigmoidf_(zi) * tanhf_(zg);
        float h_new = sigmoidf_(zo) * tanhf_(c_new);
        bool msk = (tok != 0);
        float h_sel = msk ? h_new : h_st;
        float c_sel = msk ? c_new : c_st;
        h_st = h_sel; c_st = c_sel;
        // agent-coherent store (write-through to L3, no dirty L2 line)
        stg_h_sc1(h + ((size_t)b_me * T_ + t) * (2 * U_) + dir * U_ + u_g,
                  (unsigned int)f2bf(h_sel));
        // drain our (untracked) sc1 store before signaling
        asm volatile("s_waitcnt vmcnt(0)" ::: "memory");
        __syncthreads();                                   // (C) all stores at L3
        if (tid == 0)
            __hip_atomic_fetch_add(&cnt[cbase + s], 1, __ATOMIC_RELAXED,
                                   __HIP_MEMORY_SCOPE_AGENT);
    }
}

// ---------------- host launch ----------------
extern "C" void kernel_launch(void* const* d_in, const int* in_sizes, int n_in,
                              void* d_out, int out_size, void* d_ws, size_t ws_size,
                              hipStream_t stream)
{
    const int*   tokens = (const int*)d_in[0];
    const float* emb  = (const float*)d_in[1];
    const float* k1f  = (const float*)d_in[2];
    const float* r1f  = (const float*)d_in[3];
    const float* b1f  = (const float*)d_in[4];
    const float* k1b  = (const float*)d_in[5];
    const float* r1b  = (const float*)d_in[6];
    const float* b1b  = (const float*)d_in[7];
    const float* k2f  = (const float*)d_in[8];
    const float* r2f  = (const float*)d_in[9];
    const float* b2f  = (const float*)d_in[10];
    const float* k2b  = (const float*)d_in[11];
    const float* r2b  = (const float*)d_in[12];
    const float* b2b  = (const float*)d_in[13];
    const float* wd   = (const float*)d_in[14];
    const float* bd   = (const float*)d_in[15];
    float* out = (float*)d_out;

    // d_out (BT*V f32 = 500 MiB) doubles as scratch until the final GEMM.
    const size_t MB = 1024 * 1024;
    ushort_t* xw   = (ushort_t*)d_out;                          // [2][BT][2048] 128 MiB bf16
    ushort_t* x    = (ushort_t*)((char*)d_out + 128 * MB);      // [BT][256]       8 MiB
    ushort_t* h1   = (ushort_t*)((char*)d_out + 136 * MB);      // [BT][1024]     32 MiB
    char* wb       = (char*)d_out + 168 * MB;                   // transposed weights (bf16)
    ushort_t* k1fT = (ushort_t*)(wb);
    ushort_t* k1bT = (ushort_t*)(wb + 1  * MB);
    ushort_t* k2fT = (ushort_t*)(wb + 2  * MB);
    ushort_t* k2bT = (ushort_t*)(wb + 6  * MB);
    ushort_t* r1fT = (ushort_t*)(wb + 10 * MB);
    ushort_t* r1bT = (ushort_t*)(wb + 12 * MB);
    ushort_t* r2fT = (ushort_t*)(wb + 14 * MB);
    ushort_t* r2bT = (ushort_t*)(wb + 16 * MB);
    // ws: counters + h2 + wdT (must survive the final GEMM) — ~48 MiB
    int*      cnt  = (int*)d_ws;                                // 2 layers * [2][T]
    ushort_t* h2   = (ushort_t*)((char*)d_ws + 65536);          // [BT][1024] 32 MiB bf16
    ushort_t* wdT  = (ushort_t*)((char*)d_ws + 65536 + (size_t)BT_ * 2 * U_ * 2);

    hipMemsetAsync(cnt, 0, 2 * 2 * T_ * sizeof(int), stream);
    embed_kernel<<<BT_ / 4, 256, 0, stream>>>(tokens, emb, x);

    transpose_f32_bf16<<<dim3(2048/32, 256/32 ), 256, 0, stream>>>(k1f, k1fT, 256,  2048);
    transpose_f32_bf16<<<dim3(2048/32, 256/32 ), 256, 0, stream>>>(k1b, k1bT, 256,  2048);
    transpose_f32_bf16<<<dim3(2048/32, 1024/32), 256, 0, stream>>>(k2f, k2fT, 1024, 2048);
    transpose_f32_bf16<<<dim3(2048/32, 1024/32), 256, 0, stream>>>(k2b, k2bT, 1024, 2048);
    transpose_f32_bf16<<<dim3(2048/32, 512/32 ), 256, 0, stream>>>(r1f, r1fT, 512,  2048);
    transpose_f32_bf16<<<dim3(2048/32, 512/32 ), 256, 0, stream>>>(r1b, r1bT, 512,  2048);
    transpose_f32_bf16<<<dim3(2048/32, 512/32 ), 256, 0, stream>>>(r2f, r2fT, 512,  2048);
    transpose_f32_bf16<<<dim3(2048/32, 512/32 ), 256, 0, stream>>>(r2b, r2bT, 512,  2048);
    transpose_f32_bf16<<<dim3(8000/32, 1024/32), 256, 0, stream>>>(wd,  wdT,  1024, 8000);

    // layer-1 input transforms
    gemm_bt<false><<<dim3(128, 16), 256, 0, stream>>>(x, k1fT, b1f, xw,                      BT_, G4_, E_);
    gemm_bt<false><<<dim3(128, 16), 256, 0, stream>>>(x, k1bT, b1b, xw + (size_t)BT_ * G4_,  BT_, G4_, E_);
    lstm_rec<<<dim3(GWG, 2), 512, 0, stream>>>(xw, r1fT, r1bT, tokens, h1, cnt);
    // layer-2 input transforms (xw region reused)
    gemm_bt<false><<<dim3(128, 16), 256, 0, stream>>>(h1, k2fT, b2f, xw,                     BT_, G4_, 2*U_);
    gemm_bt<false><<<dim3(128, 16), 256, 0, stream>>>(h1, k2bT, b2b, xw + (size_t)BT_ * G4_, BT_, G4_, 2*U_);
    lstm_rec<<<dim3(GWG, 2), 512, 0, stream>>>(xw, r2fT, r2bT, tokens, h2, cnt + 2 * T_);
    // vocab projection (f32 logits)
    gemm_bt<true><<<dim3(128, (V_ + 127) / 128), 256, 0, stream>>>(h2, wdT, bd, out, BT_, V_, 2*U_);
}